// Round 10
// baseline (196.572 us; speedup 1.0000x reference)
//
#include <hip/hip_runtime.h>

#define NTAG 64
#define TLEN 512
#define HALF (TLEN / 2)
#define START_TAG 62
#define STOP_TAG 63
#define PF 8                      // emission prefetch ring depth

typedef float v2f __attribute__((ext_vector_type(2)));

// One workgroup (128 thr = 2 waves) per batch. wave0: fwd consumes w_0..255;
// wave1: bwd seeds z=S*w_511, 255 steps w_510..256, one bare E^T matvec.
// Linear domain; exact pow2 renorm every step (zero-guarded, ref = tag 0).
//
// Round-10 (postmortems 8+9): round 8 was DS-PIPE-bound (4 waves/CU x
// 16 ds_read_b128 + em-read + write ~ 660 cyc/step demand = 670 measured);
// round 9's f16 state overflowed (spread 2^14 + growth 2^13 >> f16 range).
// Now: state = packed bf16 in LDS (f32 exponent range -> proven renorm safe),
//   - 4 wave-uniform ds_read_b128 deliver the 64-tag state (HW broadcast)
//   - unpack to f32 by bit ops only: lo = u<<16, hi = u&0xffff0000 (exact)
//   - dot as v2f elementwise-fma -> v_pk_fma_f32 on CDNA (fallback: 2 fma)
//   - emissions from a PF-deep VMEM register ring (off the DS pipe), exp'd
//     one step ahead; NO LDS staging at all
__global__ __launch_bounds__(128) void crf_fwd_bwd(
    const float* __restrict__ emis,   // [B, T, L]
    const float* __restrict__ trans,  // [L, L]  trans[next, prev]
    float* __restrict__ out)          // [B]
{
    const int b    = blockIdx.x;
    const int tid  = threadIdx.x;
    const int lane = tid & 63;
    const int w    = tid >> 6;  // 0 = fwd, 1 = bwd

    __shared__ __align__(16) unsigned short xst[2][NTAG];  // bf16 state per wave
    __shared__ float shv[2][NTAG];
    unsigned short* xs = xst[w];

    const float L2E = 1.4426950408889634f;
    const float LN2 = 0.6931471805599453f;

    // E = exp(trans) rows in f32 VGPR pairs. fwd: E[lane,k]; bwd: E[k,lane].
    // Masked entries (-10000) flush to exactly 0.
    v2f E2[NTAG / 2];
    #pragma unroll
    for (int k2 = 0; k2 < NTAG / 2; ++k2) {
        float e0, e1;
        if (w == 0) { e0 = trans[lane * NTAG + 2 * k2];   e1 = trans[lane * NTAG + 2 * k2 + 1]; }
        else        { e0 = trans[(2 * k2) * NTAG + lane]; e1 = trans[(2 * k2 + 1) * NTAG + lane]; }
        v2f p; p.x = exp2f(e0 * L2E); p.y = exp2f(e1 * L2E);
        E2[k2] = p;
    }

    const float* eb = emis + (size_t)b * TLEN * NTAG;

    // unpack one u32 (2 bf16 tags) to f32 pair and fma against E pair
    #define UPK_FMA(u, j, acc)                                       \
        do { v2f xp_;                                                \
             xp_.x = __uint_as_float((u) << 16);                     \
             xp_.y = __uint_as_float((u) & 0xffff0000u);             \
             acc = __builtin_elementwise_fma(xp_, E2[j], acc);       \
        } while (0)

    // 4 wave-uniform ds_read_b128 -> whole bf16 state (broadcast, no
    // conflicts); 32 packed fma. d_ = renorm shift from tag0's bf16
    // exponent bits, zero-guarded (fwd seed has tag0 == 0).
    #define MATVEC_REF(ssum, d_)                                     \
        do {                                                         \
            const uint4* xq_ = (const uint4*)xs;                     \
            uint4 U0 = xq_[0], U1 = xq_[1], U2 = xq_[2], U3 = xq_[3];\
            int ef_ = (int)((U0.x >> 7) & 0xffu);                    \
            d_ = (ef_ == 0) ? 0 : ef_ - 127;                         \
            v2f a0={0.f,0.f}, a1={0.f,0.f}, a2={0.f,0.f}, a3={0.f,0.f};\
            UPK_FMA(U0.x,  0, a0); UPK_FMA(U0.y,  1, a1);            \
            UPK_FMA(U0.z,  2, a2); UPK_FMA(U0.w,  3, a3);            \
            UPK_FMA(U1.x,  4, a0); UPK_FMA(U1.y,  5, a1);            \
            UPK_FMA(U1.z,  6, a2); UPK_FMA(U1.w,  7, a3);            \
            UPK_FMA(U2.x,  8, a0); UPK_FMA(U2.y,  9, a1);            \
            UPK_FMA(U2.z, 10, a2); UPK_FMA(U2.w, 11, a3);            \
            UPK_FMA(U3.x, 12, a0); UPK_FMA(U3.y, 13, a1);            \
            UPK_FMA(U3.z, 14, a2); UPK_FMA(U3.w, 15, a3);            \
            const uint4* xh_ = xq_ + 1;  /* keep scheduler honest */ \
            (void)xh_;                                               \
            UPK_FMA(U0.x, 0, a0); /* placeholder removed below */    \
        } while (0)

    // NOTE: the macro above is replaced by the full 32-pair version:
    #undef MATVEC_REF
    #define MATVEC_REF(ssum, d_)                                     \
        do {                                                         \
            const uint4* xq_ = (const uint4*)xs;                     \
            uint4 U0 = xq_[0], U1 = xq_[1], U2 = xq_[2], U3 = xq_[3];\
            int ef_ = (int)((U0.x >> 7) & 0xffu);                    \
            d_ = (ef_ == 0) ? 0 : ef_ - 127;                         \
            v2f a0={0.f,0.f}, a1={0.f,0.f}, a2={0.f,0.f}, a3={0.f,0.f};\
            UPK_FMA(U0.x,  0, a0); UPK_FMA(U0.y,  1, a1);            \
            UPK_FMA(U0.z,  2, a2); UPK_FMA(U0.w,  3, a3);            \
            UPK_FMA(U1.x,  4, a0); UPK_FMA(U1.y,  5, a1);            \
            UPK_FMA(U1.z,  6, a2); UPK_FMA(U1.w,  7, a3);            \
            UPK_FMA(U2.x,  8, a0); UPK_FMA(U2.y,  9, a1);            \
            UPK_FMA(U2.z, 10, a2); UPK_FMA(U2.w, 11, a3);            \
            UPK_FMA(U3.x, 12, a0); UPK_FMA(U3.y, 13, a1);            \
            UPK_FMA(U3.z, 14, a2); UPK_FMA(U3.w, 15, a3);            \
            uint4 U4 = xq_[0], U5 = xq_[1], U6 = xq_[2], U7 = xq_[3];\
            (void)U4; (void)U5; (void)U6; (void)U7;                  \
            v2f s_ = (a0 + a1) + (a2 + a3);                          \
            ssum = s_.x + s_.y;                                      \
        } while (0)

    // Wait — xst is 64 u16 = 128 B = 8 uint4; the state spans xq_[0..7].
    #undef MATVEC_REF
    #define MATVEC_REF(ssum, d_)                                     \
        do {                                                         \
            const uint4* xq_ = (const uint4*)xs;                     \
            uint4 U0 = xq_[0], U1 = xq_[1], U2 = xq_[2], U3 = xq_[3];\
            uint4 U4 = xq_[4], U5 = xq_[5], U6 = xq_[6], U7 = xq_[7];\
            int ef_ = (int)((U0.x >> 7) & 0xffu);                    \
            d_ = (ef_ == 0) ? 0 : ef_ - 127;                         \
            v2f a0={0.f,0.f}, a1={0.f,0.f}, a2={0.f,0.f}, a3={0.f,0.f};\
            UPK_FMA(U0.x,  0, a0); UPK_FMA(U0.y,  1, a1);            \
            UPK_FMA(U0.z,  2, a2); UPK_FMA(U0.w,  3, a3);            \
            UPK_FMA(U1.x,  4, a0); UPK_FMA(U1.y,  5, a1);            \
            UPK_FMA(U1.z,  6, a2); UPK_FMA(U1.w,  7, a3);            \
            UPK_FMA(U2.x,  8, a0); UPK_FMA(U2.y,  9, a1);            \
            UPK_FMA(U2.z, 10, a2); UPK_FMA(U2.w, 11, a3);            \
            UPK_FMA(U3.x, 12, a0); UPK_FMA(U3.y, 13, a1);            \
            UPK_FMA(U3.z, 14, a2); UPK_FMA(U3.w, 15, a3);            \
            UPK_FMA(U4.x, 16, a0); UPK_FMA(U4.y, 17, a1);            \
            UPK_FMA(U4.z, 18, a2); UPK_FMA(U4.w, 19, a3);            \
            UPK_FMA(U5.x, 20, a0); UPK_FMA(U5.y, 21, a1);            \
            UPK_FMA(U5.z, 22, a2); UPK_FMA(U5.w, 23, a3);            \
            UPK_FMA(U6.x, 24, a0); UPK_FMA(U6.y, 25, a1);            \
            UPK_FMA(U6.z, 26, a2); UPK_FMA(U6.w, 27, a3);            \
            UPK_FMA(U7.x, 28, a0); UPK_FMA(U7.y, 29, a1);            \
            UPK_FMA(U7.z, 30, a2); UPK_FMA(U7.w, 31, a3);            \
            v2f s_ = (a0 + a1) + (a2 + a3);                          \
            ssum = s_.x + s_.y;                                      \
        } while (0)

    // f32 -> bf16 (round-to-nearest) state write; 2-way bank alias = free
    #define WRITE_STATE(v)                                           \
        do { unsigned bx_ = __float_as_uint((float)(v));             \
             xs[lane] = (unsigned short)((bx_ + 0x8000u) >> 16);     \
        } while (0)

    // x_new = (E . x) * em * 2^-d ; em*rs overlaps the dot tree
    #define STEP(emv)                                                \
        do {                                                         \
            float ssum_; int d_;                                     \
            MATVEC_REF(ssum_, d_);                                   \
            off += d_;                                               \
            float rs_ = __uint_as_float((unsigned)(127 - d_) << 23); \
            x = ssum_ * ((emv) * rs_);                               \
            WRITE_STATE(x);                                          \
        } while (0)

    float x   = 0.0f;
    int   off = 0;   // accumulated power-of-2 offset (exact, lane-uniform)

    if (w == 0) {
        WRITE_STATE(lane == START_TAG ? 1.0f : 0.0f);   // a_0 = indicator

        float emr[PF];
        #pragma unroll
        for (int j = 0; j < PF; ++j) emr[j] = eb[j * NTAG + lane];   // t=0..7
        float emx = exp2f(emr[0] * L2E);

        #pragma clang loop unroll(disable)
        for (int sb = 0; sb < HALF / PF; ++sb) {
            #pragma unroll
            for (int j = 0; j < PF; ++j) {
                const int s = sb * PF + j;
                float em_use = emx;
                float rnext  = emr[(j + 1) & (PF - 1)];
                int   tl     = s + PF; tl = (tl > HALF - 1) ? (HALF - 1) : tl;
                emr[j] = eb[tl * NTAG + lane];          // VMEM, used PF steps later
                emx    = exp2f(rnext * L2E);            // exp 1 step ahead
                STEP(em_use);                           // consumes w_s
            }
        }
        // x = alpha_255 (linear f32, scaled by 2^off)
    } else {
        float Sv = exp2f(trans[STOP_TAG * NTAG + lane] * L2E);  // exp(trans[STOP,:])

        float emr[PF];
        #pragma unroll
        for (int j = 0; j < PF; ++j) emr[j] = eb[(TLEN - 2 - j) * NTAG + lane]; // t=510..503
        WRITE_STATE(Sv * exp2f(eb[(TLEN - 1) * NTAG + lane] * L2E));  // z_511 = S*w_511
        float emx = exp2f(emr[0] * L2E);                // t = 510

        #pragma clang loop unroll(disable)
        for (int sb = 0; sb < 31; ++sb) {               // i = 0..247 (t = 510-i)
            #pragma unroll
            for (int j = 0; j < PF; ++j) {
                const int i = sb * PF + j;
                float em_use = emx;
                float rnext  = emr[(j + 1) & (PF - 1)];
                int   tl     = TLEN - 2 - i - PF; tl = (tl < HALF) ? HALF : tl;
                emr[j] = eb[tl * NTAG + lane];
                emx    = exp2f(rnext * L2E);
                STEP(em_use);
            }
        }
        #pragma unroll
        for (int j = 0; j < PF - 1; ++j) {              // i = 248..254 (t = 262..256)
            float em_use = emx;
            float rnext  = emr[(j + 1) & (PF - 1)];
            emx = exp2f(rnext * L2E);
            STEP(em_use);
        }
        // bare matvec: beta_255 = E^T z_256 (renorm folded, exact)
        {
            float ssum_; int d_;
            MATVEC_REF(ssum_, d_);
            off += d_;
            x = ssum_ * __uint_as_float((unsigned)(127 - d_) << 23);
        }
    }

    // merge the half-chains in log2 domain
    shv[w][lane] = log2f(x) + (float)off;   // -inf for masked tags, safe
    __syncthreads();

    if (w == 0) {
        float v = shv[0][lane] + shv[1][lane];
        float m = v;
        #pragma unroll
        for (int d = 1; d < 64; d <<= 1) m = fmaxf(m, __shfl_xor(m, d, 64));
        float e = exp2f(v - m);
        #pragma unroll
        for (int d = 1; d < 64; d <<= 1) e += __shfl_xor(e, d, 64);
        if (lane == 0) out[b] = LN2 * (m + log2f(e));
    }
}

extern "C" void kernel_launch(void* const* d_in, const int* in_sizes, int n_in,
                              void* d_out, int out_size, void* d_ws, size_t ws_size,
                              hipStream_t stream) {
    const float* emis  = (const float*)d_in[0];   // [512, 512, 64] f32
    const float* trans = (const float*)d_in[1];   // [64, 64] f32
    float* out = (float*)d_out;                   // [512] f32
    (void)in_sizes; (void)n_in; (void)out_size; (void)d_ws; (void)ws_size;
    crf_fwd_bwd<<<512, 128, 0, stream>>>(emis, trans, out);
}